// Round 7
// baseline (208.414 us; speedup 1.0000x reference)
//
#include <hip/hip_runtime.h>
#include <hip/hip_bf16.h>

// CTC batch cost — split-phase, LINEAR-domain f64 recurrence, 2-step fused.
// Phase 1: 4 waves fill LDS table lp[t][j] = (p[t][ext_j]+eps)*128 (f32).
// Phase 2: wave 0 runs alpha recurrence in linear f64 (scaled by 128^(t+1)).
//   Two timesteps per iteration share ONE cross-lane round: lane i redundantly
//   computes neighbor's odd update nh_{i-1} from shfl_up(hi,1|2), shfl_up(lo,1).
// Final: loss = 256*ln(128) - ln(alpha[64]+alpha[63]).
// B=1024, T=256, C=128, L=32, S=65, blank=127.

#define CTC_B 1024
#define CTC_T 256
#define CTC_C 128
#define CTC_L 32
#define CTC_BLANK 127
#define CTC_EPS 1e-7f

#define RSTRIDE 33   // 32 labels + 1 blank per timestep

__global__ __launch_bounds__(256) void ctc_loss_kernel(
    const int* __restrict__ y_true,   // [B, L] int32
    const float* __restrict__ y_pred, // [B, T, C] float32
    float* __restrict__ out)          // [B, 1] float32
{
    __shared__ float lp[CTC_T * RSTRIDE];  // 33.8 KB -> 4 blocks/CU

    const int b = blockIdx.x;
    const int tid = threadIdx.x;
    const int lane = tid & 63;
    const int wave = tid >> 6;

    const float* yp = y_pred + (size_t)b * CTC_T * CTC_C;

    // per-lane gather label: lanes 0..31 -> y_true, lanes 32..63 -> blank
    int lbl = CTC_BLANK;
    if (lane < CTC_L) lbl = y_true[b * CTC_L + lane];

    // ---- phase 1: wave w handles t in [w*64, w*64+64) ----
    {
        const int t0 = wave * 64;
        #pragma unroll 8
        for (int k = 0; k < 64; ++k) {
            int t = t0 + k;
            float p = yp[t * CTC_C + lbl];
            float v = (p + CTC_EPS) * 128.0f;   // scaled linear prob
            if (lane <= 32) lp[t * RSTRIDE + lane] = v;
        }
    }
    __syncthreads();

    if (wave != 0) return;

    // ---- phase 2: lane i owns alpha[2i] (lo) and alpha[2i+1] (hi), f64 ----
    double skip = 0.0;
    if (lane >= 1 && lane < CTC_L) {
        int prev = y_true[b * CTC_L + lane - 1];
        if (prev != lbl) skip = 1.0;   // labels are never blank
    }
    double skipm1 = __shfl_up(skip, 1);
    if (lane == 0) skipm1 = 0.0;

    const int lidx   = (lane < 32) ? lane : 32;  // lanes>=32 read blank slot
    const int lidxm1 = (lidx > 0) ? (lidx - 1) : 0;
    const bool alive = (lane < 32);              // lanes with a real odd state

    double lo = 0.0, hi = 0.0;
    if (lane == 0) {
        lo = (double)lp[32];   // alpha[0] = (p_blank+eps)*128 @ t=0
        hi = (double)lp[0];    // alpha[1] = (p_label0+eps)*128 @ t=0
    }

    // ---- t = 1: single step (255 remaining steps; 254 done fused) ----
    {
        float pvf = lp[RSTRIDE + lidx];
        float pbf = lp[RSTRIDE + 32];
        double pv = alive ? (double)pvf : 0.0;
        double pb = (double)pbf;
        double ph = __shfl_up(hi, 1);
        if (lane == 0) ph = 0.0;
        double nl = (lo + ph) * pb;
        double nh = (hi + lo + skip * ph) * pv;
        lo = nl; hi = nh;
    }

    // ---- fused pairs: t, t+1 for t = 2,4,...,254 ----
    for (int t = 2; t < CTC_T; t += 2) {
        // ONE cross-lane round per 2 steps (3 parallel shuffles)
        double h1 = __shfl_up(hi, 1);   // hi_{i-1}
        double l1 = __shfl_up(lo, 1);   // lo_{i-1}
        double h2 = __shfl_up(hi, 2);   // hi_{i-2}
        if (lane == 0) { h1 = 0.0; l1 = 0.0; }
        if (lane <= 1) { h2 = 0.0; }

        float pv0f = lp[t * RSTRIDE + lidx];
        float pm0f = lp[t * RSTRIDE + lidxm1];
        float pb0f = lp[t * RSTRIDE + 32];
        float pv1f = lp[(t + 1) * RSTRIDE + lidx];
        float pb1f = lp[(t + 1) * RSTRIDE + 32];
        double pv0 = alive ? (double)pv0f : 0.0;
        double pv1 = alive ? (double)pv1f : 0.0;
        double pm0 = (double)pm0f;      // neighbor's label prob at t
        double pb0 = (double)pb0f;
        double pb1 = (double)pb1f;

        // step t (own states + replica of neighbor's odd state)
        double nl  = (lo + h1) * pb0;
        double nh  = (hi + lo + skip   * h1) * pv0;
        double nhm = (h1 + l1 + skipm1 * h2) * pm0;   // nh_{i-1} replica
        // step t+1 (uses only locally-available values)
        lo = (nl + nhm) * pb1;
        hi = (nh + nl + skip * nhm) * pv1;
    }

    // loss = 256*ln(128) - ln(alpha[64] + alpha[63])
    double aS1 = __shfl(lo, 32);   // alpha[64]
    double aS2 = __shfl(hi, 31);   // alpha[63]
    if (lane == 0) {
        out[b] = (float)(1242.1197475634219 - log(aS1 + aS2));
    }
}

extern "C" void kernel_launch(void* const* d_in, const int* in_sizes, int n_in,
                              void* d_out, int out_size, void* d_ws, size_t ws_size,
                              hipStream_t stream) {
    const int*   y_true = (const int*)d_in[0];
    const float* y_pred = (const float*)d_in[1];
    float*       out    = (float*)d_out;

    ctc_loss_kernel<<<CTC_B, 256, 0, stream>>>(y_true, y_pred, out);
}